// Round 8
// baseline (85.494 us; speedup 1.0000x reference)
//
#include <hip/hip_runtime.h>
#include <math.h>

#define HID 1024
#define SEQ 4096
#define NB 16
#define CHUNK 64
#define NCHUNK (SEQ / CHUNK)   // 64

// ---------------------------------------------------------------------------
// Kernel A: hp = tanh(t @ W_p + b_p); blkPart[b][blk] = partial of hp·v_p.
// grid 64 blocks (16 W_p columns each), block 256 = 16 batches x 16 cols.
// W_p is read EXACTLY ONCE (4 MB total, was 64 MB with per-batch blocks).
// All 16 batches' targets staged in LDS; fp64 math throughout.
// ---------------------------------------------------------------------------
__global__ __launch_bounds__(256) void kA(const float* __restrict__ tgt,
                                          const float* __restrict__ Wp,
                                          const float* __restrict__ bp,
                                          const float* __restrict__ vp,
                                          double* __restrict__ blkPart) {
  // tl[b][h], padded stride 1032 floats: bank = (b*8 + h) % 32 -> the 4
  // b-groups of a wave hit 4 distinct banks (conflict-free broadcast).
  __shared__ float tl[NB][1032];
  const int blk = blockIdx.x;
  const int j0 = blk * 16;
  const int tid = threadIdx.x;

  #pragma unroll
  for (int i = 0; i < 64; ++i) {
    const int f = i * 256 + tid;         // 0..16383 over (b,h)
    tl[f >> 10][f & 1023] = tgt[f];
  }
  __syncthreads();

  const int j = tid & 15;   // column within block's 16-col stripe
  const int b = tid >> 4;   // batch
  const float* wp = Wp + j0 + j;

  double a0 = 0.0, a1 = 0.0, a2 = 0.0, a3 = 0.0;
  for (int h = 0; h < HID; h += 4) {
    a0 += (double)tl[b][h + 0] * (double)wp[(size_t)(h + 0) * HID];
    a1 += (double)tl[b][h + 1] * (double)wp[(size_t)(h + 1) * HID];
    a2 += (double)tl[b][h + 2] * (double)wp[(size_t)(h + 2) * HID];
    a3 += (double)tl[b][h + 3] * (double)wp[(size_t)(h + 3) * HID];
  }
  const double s = (a0 + a1) + (a2 + a3);
  double val = tanh(s + (double)bp[j0 + j]) * (double)vp[j0 + j];

  // reduce over the 16 j's (consecutive lanes, same wave)
  #pragma unroll
  for (int off = 1; off < 16; off <<= 1) val += __shfl_xor(val, off);
  if (j == 0) blkPart[b * 64 + blk] = val;   // layout [b][blk]
}

// ---------------------------------------------------------------------------
// Kernel B: fused score+exp+gauss+context partial, single streamed read of src.
// grid 1024 (16 batches x 64 chunks of 64 rows), block 256 (4 waves x 16 rows).
// Plain float4 loads (NT dropped this round for A/B), 2-deep row dbuf,
// shfl_xor reduce, tf pre-scaled by 1/sqrt(H). p finalized in prologue from
// blkPart (identical deterministic fp64 sum in every block).
// ---------------------------------------------------------------------------
__global__ __launch_bounds__(256) void kB(const float* __restrict__ src,
                                          const float* __restrict__ tgt,
                                          const double* __restrict__ blkPart,
                                          const float* __restrict__ bv,
                                          float* __restrict__ zPart,
                                          float* __restrict__ ctxPart) {
  const int chunk = blockIdx.x;      // 0..1023
  const int b = chunk >> 6;
  const int c = chunk & 63;
  const int tid = threadIdx.x;
  const int wave = tid >> 6;
  const int lane = tid & 63;

  // finalize p for this batch (deterministic fp64 sum of 64 partials)
  double lg = (double)bv[0];
  const double* bpart = blkPart + b * 64;
  for (int i = 0; i < 64; ++i) lg += bpart[i];
  const float pb = (float)(4096.0 / (1.0 + exp(-lg)));

  const int srow0 = c * CHUNK + wave * 16;

  // target fragment (16 floats per lane), pre-scaled by 1/sqrt(H)
  float4 tf[4];
  const float4* tg4 = (const float4*)(tgt + b * HID);
  #pragma unroll
  for (int k = 0; k < 4; ++k) {
    tf[k] = tg4[k * 64 + lane];
    tf[k].x *= 0.03125f; tf[k].y *= 0.03125f;
    tf[k].z *= 0.03125f; tf[k].w *= 0.03125f;
  }

  float4 acc[4];
  #pragma unroll
  for (int k = 0; k < 4; ++k) acc[k] = make_float4(0.f, 0.f, 0.f, 0.f);
  float z = 0.f;

  const float4* base = (const float4*)(src + ((size_t)b * SEQ + srow0) * HID);

  float4 x[2][4];
  #pragma unroll
  for (int k = 0; k < 4; ++k) x[0][k] = base[k * 64 + lane];

  #pragma unroll
  for (int r = 0; r < 16; ++r) {
    const int cur = r & 1, nxt = cur ^ 1;
    if (r + 1 < 16) {
      #pragma unroll
      for (int k = 0; k < 4; ++k)
        x[nxt][k] = base[(r + 1) * 256 + k * 64 + lane];
    }

    float d[4];
    #pragma unroll
    for (int k = 0; k < 4; ++k) {
      float t0 = x[cur][k].x * tf[k].x;
      t0 = fmaf(x[cur][k].y, tf[k].y, t0);
      t0 = fmaf(x[cur][k].z, tf[k].z, t0);
      t0 = fmaf(x[cur][k].w, tf[k].w, t0);
      d[k] = t0;
    }
    float dot = (d[0] + d[1]) + (d[2] + d[3]);
    #pragma unroll
    for (int off = 32; off; off >>= 1) dot += __shfl_xor(dot, off);

    const float w = __expf(dot);            // dot = score/sqrt(H) already
    const float ds = (float)(srow0 + r) - pb;
    const float g = __expf(ds * ds * (-1.0f / 2048.0f));
    z += w;
    const float wg = w * g;
    #pragma unroll
    for (int k = 0; k < 4; ++k) {
      acc[k].x = fmaf(wg, x[cur][k].x, acc[k].x);
      acc[k].y = fmaf(wg, x[cur][k].y, acc[k].y);
      acc[k].z = fmaf(wg, x[cur][k].z, acc[k].z);
      acc[k].w = fmaf(wg, x[cur][k].w, acc[k].w);
    }
  }

  // combine 4 waves via LDS
  __shared__ float lctx[4][HID];
  __shared__ float lz[4];
  #pragma unroll
  for (int k = 0; k < 4; ++k)
    *(float4*)&lctx[wave][k * 256 + lane * 4] = acc[k];
  if (lane == 0) lz[wave] = z;
  __syncthreads();

  float4 s4 = make_float4(0.f, 0.f, 0.f, 0.f);
  #pragma unroll
  for (int w2 = 0; w2 < 4; ++w2) {
    float4 v = *(const float4*)&lctx[w2][tid * 4];
    s4.x += v.x; s4.y += v.y; s4.z += v.z; s4.w += v.w;
  }
  ((float4*)ctxPart)[(size_t)chunk * 256 + tid] = s4;
  if (tid == 0) zPart[chunk] = lz[0] + lz[1] + lz[2] + lz[3];
}

// ---------------------------------------------------------------------------
// Kernel C: combine chunk partials, divide by Z.
// grid (16 batches, 16 hsegs of 64 cols), block 256 (4 chunk-groups x 64 cols).
// ---------------------------------------------------------------------------
__global__ __launch_bounds__(256) void kC(const float* __restrict__ zPart,
                                          const float* __restrict__ ctxPart,
                                          float* __restrict__ out) {
  __shared__ float red[4][64];
  const int b = blockIdx.x;
  const int hseg = blockIdx.y;
  const int tid = threadIdx.x;
  const int col = tid & 63;
  const int grp = tid >> 6;

  float acc = 0.f;
  #pragma unroll
  for (int i = 0; i < 16; ++i) {
    const int chunk = grp * 16 + i;
    acc += ctxPart[((size_t)(b * NCHUNK + chunk)) * HID + hseg * 64 + col];
  }
  red[grp][col] = acc;
  __syncthreads();

  if (tid < 64) {
    float Z = 0.f;
    for (int c = 0; c < NCHUNK; ++c) Z += zPart[b * NCHUNK + c];
    const float s = red[0][tid] + red[1][tid] + red[2][tid] + red[3][tid];
    out[b * HID + hseg * 64 + tid] = s / Z;
  }
}

// ---------------------------------------------------------------------------
extern "C" void kernel_launch(void* const* d_in, const int* in_sizes, int n_in,
                              void* d_out, int out_size, void* d_ws, size_t ws_size,
                              hipStream_t stream) {
  const float* src = (const float*)d_in[0];   // (16, 4096, 1024)
  const float* tgt = (const float*)d_in[1];   // (16, 1024)
  const float* Wp  = (const float*)d_in[2];   // (1024, 1024)
  const float* bp  = (const float*)d_in[3];   // (1024,)
  const float* vp  = (const float*)d_in[4];   // (1024,)
  const float* bv  = (const float*)d_in[5];   // scalar
  float* out = (float*)d_out;

  double* blkPart = (double*)d_ws;                         // 16 x 64 doubles (8 KB)
  float* zPart    = (float*)((char*)d_ws + 8192);          // 1024 floats
  float* ctxPart  = (float*)((char*)d_ws + 16384);         // 4 MB

  kA<<<64, 256, 0, stream>>>(tgt, Wp, bp, vp, blkPart);
  kB<<<NB * NCHUNK, 256, 0, stream>>>(src, tgt, blkPart, bv, zPart, ctxPart);
  kC<<<dim3(NB, 16), 256, 0, stream>>>(zPart, ctxPart, out);
}